// Round 1
// 627.653 us; speedup vs baseline: 1.5132x; 1.5132x over previous
//
#include <hip/hip_runtime.h>

// SparsTriangularUpdate on MI355X (gfx950).
// nnz=240000, C_IN=256, C_CH=128, K=12.
// R3: latency-bound fix round. XOR-swizzled LDS tiles (conflict-free reads AND
// writes), MFMA-tiled pre-swizzled weights (1KB coalesced B loads), K2 A-ops
// staged in LDS, LDS atomics replaced by raw-array + block reduce.

#define NNZ   240000
#define ROWS  64
#define NBLK  (NNZ / ROWS)   // 3750
#define PSLOTS 32

typedef __attribute__((ext_vector_type(8))) short bf16x8;
typedef __attribute__((ext_vector_type(4))) float f32x4;

__device__ __forceinline__ unsigned short f2bf(float f) {
  unsigned int u = __float_as_uint(f);
  u += 0x7fffu + ((u >> 16) & 1u);   // round-to-nearest-even
  return (unsigned short)(u >> 16);
}
__device__ __forceinline__ float bf2f(unsigned short h) {
  return __uint_as_float(((unsigned int)h) << 16);
}

// ---------------------------------------------------------------------------
// prep: fp32->bf16 weights into MFMA-tiled (lane-linear) layouts + zero bufs.
// wcat ushort index o: w8=o&7, c=o>>3, m=c&15, q=(c>>4)&3, t=(c>>6)&3,
//   kb=(c>>8)&7, wv=c>>11 -> logical row n=wv*64+t*16+m, col k=kb*32+q*8+w8.
//   So in K1, B[t] for (wv,kb) is the 1KB chunk at ((wv*8+kb)*4+t)*64 + lane.
// wgo tiles: nt in [0,2): chunk ((wv*8+kb)*2+nt)*64 + lane (rows wv*32+nt*16+m)
// wlo tiles: kb in [0,4): chunk ((wv*4+kb)*2+nt)*64 + lane
// ---------------------------------------------------------------------------
__global__ __launch_bounds__(256) void prep_kernel(
    const float* __restrict__ Wga, const float* __restrict__ Wla,
    const float* __restrict__ Wgb, const float* __restrict__ Wlb,
    const float* __restrict__ Wgo, const float* __restrict__ Wlo,
    unsigned short* __restrict__ wcat, unsigned short* __restrict__ wgo16,
    unsigned short* __restrict__ wlo16, float* __restrict__ bsum,
    float* __restrict__ bpart)
{
  const int tid = blockIdx.x * 256 + threadIdx.x;
  if (tid < 12 * 128) bsum[tid] = 0.f;
  if (tid < PSLOTS * 1536) bpart[tid] = 0.f;
  if (tid < 131072) {                 // Wcat: 512 x 256 -> tiled
    const int w8 = tid & 7, c = tid >> 3;
    const int m = c & 15, q = (c >> 4) & 3, t = (c >> 6) & 3;
    const int kb = (c >> 8) & 7, wv = c >> 11;
    const int k = kb * 32 + q * 8 + w8;
    const int ch = ((wv & 3) << 5) + ((t & 1) << 4) + m;
    const float* src = (wv < 4) ? (t < 2 ? Wga : Wla) : (t < 2 ? Wgb : Wlb);
    wcat[tid] = f2bf(src[ch * 256 + k]);
  } else if (tid < 196608) {          // W_go: 256 x 256 -> tiled
    const int o = tid - 131072;
    const int w8 = o & 7, c = o >> 3;
    const int m = c & 15, q = (c >> 4) & 3, nt = (c >> 6) & 1;
    const int kb = (c >> 7) & 7, wv = c >> 10;
    wgo16[o] = f2bf(Wgo[(wv * 32 + nt * 16 + m) * 256 + kb * 32 + q * 8 + w8]);
  } else if (tid < 229376) {          // W_lo: 256 x 128 -> tiled
    const int o = tid - 196608;
    const int w8 = o & 7, c = o >> 3;
    const int m = c & 15, q = (c >> 4) & 3, nt = (c >> 6) & 1;
    const int kb = (c >> 7) & 3, wv = c >> 9;
    wlo16[o] = f2bf(Wlo[(wv * 32 + nt * 16 + m) * 128 + kb * 32 + q * 8 + w8]);
  }
}

// ---------------------------------------------------------------------------
// K1: LN(values) -> x (bf16, swizzled x_ws + swizzled LDS); per-wave 64x64
// MFMA vs tiled Wcat; gate; a -> a_ws (linear); b -> raw LDS array ->
// block-level reduce -> striped global partial (atomic, slot blk&31).
// LDS swizzle: 16B chunk c of row r lives at chunk c ^ (r&7).
//   LN write: thread (r,j) owns chunks {j,j+8,j+16,j+24} -> per-8-lane-group
//   slots j^(r&7) distinct -> conflict-free ds_write_b128.
//   MFMA A read: chunk (kb*4+q)^(m&7), 8-lane groups get distinct slots.
// ---------------------------------------------------------------------------
__global__ __launch_bounds__(512, 4) void k1_kernel(
    const float* __restrict__ values,
    const float* __restrict__ ln_g, const float* __restrict__ ln_b,
    const float* __restrict__ b_ga, const float* __restrict__ b_la,
    const float* __restrict__ b_gb, const float* __restrict__ b_lb,
    const unsigned short* __restrict__ wcat,
    unsigned short* __restrict__ x_ws,
    unsigned short* __restrict__ a_ws,
    float* __restrict__ bpart)
{
  __shared__ unsigned short x_lds[ROWS][256];   // swizzled, no pad (32KB)
  __shared__ float b_raw[ROWS][132];            // +4 pad -> 2-way banks (free)
  const int tid = threadIdx.x;
  const int rbase = blockIdx.x * ROWS;

  // ---- LayerNorm: 8 threads per row; thread j owns chunks {j+8i} ----
  {
    const int r = tid >> 3, j = tid & 7;
    const size_t grow = (size_t)(rbase + r) * 256;
    float4 v[8];
    float s1 = 0.f, s2 = 0.f;
#pragma unroll
    for (int i = 0; i < 4; i++) {
      const int e = (j + 8 * i) * 8;
      const float4 t0 = *(const float4*)(values + grow + e);
      const float4 t1 = *(const float4*)(values + grow + e + 4);
      v[2 * i] = t0; v[2 * i + 1] = t1;
      s1 += t0.x + t0.y + t0.z + t0.w + t1.x + t1.y + t1.z + t1.w;
      s2 += t0.x * t0.x + t0.y * t0.y + t0.z * t0.z + t0.w * t0.w
          + t1.x * t1.x + t1.y * t1.y + t1.z * t1.z + t1.w * t1.w;
    }
    s1 += __shfl_xor(s1, 1); s1 += __shfl_xor(s1, 2); s1 += __shfl_xor(s1, 4);
    s2 += __shfl_xor(s2, 1); s2 += __shfl_xor(s2, 2); s2 += __shfl_xor(s2, 4);
    const float mu = s1 * (1.f / 256.f);
    const float rstd = rsqrtf(s2 * (1.f / 256.f) - mu * mu + 1e-5f);
    const int jp = j ^ (r & 7);
#pragma unroll
    for (int i = 0; i < 4; i++) {
      const int e = (j + 8 * i) * 8;       // logical element base
      const float4 a0 = v[2 * i], a1 = v[2 * i + 1];
      const float4 g0 = *(const float4*)(ln_g + e);
      const float4 g1 = *(const float4*)(ln_g + e + 4);
      const float4 c0 = *(const float4*)(ln_b + e);
      const float4 c1 = *(const float4*)(ln_b + e + 4);
      bf16x8 h;
      h[0] = (short)f2bf((a0.x - mu) * rstd * g0.x + c0.x);
      h[1] = (short)f2bf((a0.y - mu) * rstd * g0.y + c0.y);
      h[2] = (short)f2bf((a0.z - mu) * rstd * g0.z + c0.z);
      h[3] = (short)f2bf((a0.w - mu) * rstd * g0.w + c0.w);
      h[4] = (short)f2bf((a1.x - mu) * rstd * g1.x + c1.x);
      h[5] = (short)f2bf((a1.y - mu) * rstd * g1.y + c1.y);
      h[6] = (short)f2bf((a1.z - mu) * rstd * g1.z + c1.z);
      h[7] = (short)f2bf((a1.w - mu) * rstd * g1.w + c1.w);
      const int p = (jp + 8 * i) * 8;      // swizzled position (ushorts)
      *(bf16x8*)(x_ws + grow + p) = h;     // x_ws stored TILE-SWIZZLED
      *(bf16x8*)&x_lds[r][p] = h;
    }
  }
  __syncthreads();

  // ---- MFMA: wave wv owns 64 rows x 64 Wcat rows (4 N-tiles), K=256 ----
  const int wv = tid >> 6;
  const int lane = tid & 63;
  const int m = lane & 15, q = lane >> 4;

  f32x4 acc[4][4];
#pragma unroll
  for (int a = 0; a < 4; a++)
#pragma unroll
    for (int b = 0; b < 4; b++) acc[a][b] = (f32x4){0.f, 0.f, 0.f, 0.f};

#pragma unroll
  for (int kb = 0; kb < 8; kb++) {
    bf16x8 A[4], B[4];
#pragma unroll
    for (int mt = 0; mt < 4; mt++)
      A[mt] = *(const bf16x8*)&x_lds[mt * 16 + m][((kb * 4 + q) ^ (m & 7)) << 3];
#pragma unroll
    for (int t = 0; t < 4; t++)   // 1KB lane-linear tile load
      B[t] = *(const bf16x8*)(wcat + ((((wv * 8 + kb) * 4 + t) * 64 + lane) << 3));
#pragma unroll
    for (int t = 0; t < 4; t++)
#pragma unroll
      for (int mt = 0; mt < 4; mt++)
        acc[mt][t] = __builtin_amdgcn_mfma_f32_16x16x32_bf16(A[mt], B[t], acc[mt][t], 0, 0, 0);
  }

  // ---- epilogue: tiles 0,1 = gate, 2,3 = lin; a -> global, b -> raw LDS ----
  const bool isA = (wv < 4);
  const int chbase = (wv & 3) * 32;
  const float* bgp = isA ? b_ga : b_gb;
  const float* blp = isA ? b_la : b_lb;
#pragma unroll
  for (int t = 0; t < 2; t++) {
    const int ch = chbase + t * 16 + m;
    const float bgv = bgp[ch], blv = blp[ch];
#pragma unroll
    for (int mt = 0; mt < 4; mt++) {
#pragma unroll
      for (int rg = 0; rg < 4; rg++) {
        const int lrow = mt * 16 + q * 4 + rg;
        const float gv = acc[mt][t][rg] + bgv;
        const float lv = acc[mt][t + 2][rg] + blv;
        const float val = lv / (1.f + __expf(-gv));
        if (isA) {
          a_ws[(size_t)(rbase + lrow) * 128 + ch] = f2bf(val);
        } else {
          b_raw[lrow][ch] = val;       // plain store, 2-way banks (free)
        }
      }
    }
  }
  __syncthreads();

  // ---- block b-reduction (no LDS atomics): thread owns 3 (k12,ch) slots ----
  const int rb12 = rbase % 12;
  float* dst = bpart + (blockIdx.x & (PSLOTS - 1)) * 1536;
#pragma unroll
  for (int it = 0; it < 3; it++) {
    const int s = tid + it * 512;
    const int k12 = s >> 7, ch = s & 127;
    int r0 = k12 - rb12; if (r0 < 0) r0 += 12;
    float sum = 0.f;
    for (int r = r0; r < ROWS; r += 12) sum += b_raw[r][ch];
    atomicAdd(&dst[s], sum);
  }
}

// ---------------------------------------------------------------------------
// reduce: bsum[c] = sum over 32 slots of bpart
// ---------------------------------------------------------------------------
__global__ __launch_bounds__(256) void reduce_kernel(
    const float* __restrict__ bpart, float* __restrict__ bsum)
{
  const int c = blockIdx.x * 256 + threadIdx.x;   // grid 6 -> 1536 threads
  float s = 0.f;
#pragma unroll
  for (int sl = 0; sl < PSLOTS; sl++) s += bpart[sl * 1536 + c];
  bsum[c] = s;
}

// ---------------------------------------------------------------------------
// K2: stage swizzled X tile to LDS (lane-linear copies); tri = a*bsum[row%12]
// -> LN(128) -> swizzled t_lds; both GEMM A-ops from LDS, B from tiled wgo/wlo
// out = sigmoid(X @ Wgo^T + b_go) * (T @ Wlo^T + b_lo)
// ---------------------------------------------------------------------------
__global__ __launch_bounds__(512, 4) void k2_kernel(
    const unsigned short* __restrict__ x_ws,
    const unsigned short* __restrict__ a_ws,
    const float* __restrict__ bsum,
    const float* __restrict__ ln_g, const float* __restrict__ ln_b,
    const unsigned short* __restrict__ wgo,
    const unsigned short* __restrict__ wlo,
    const float* __restrict__ b_go, const float* __restrict__ b_lo,
    float* __restrict__ out)
{
  __shared__ unsigned short x_lds[ROWS][256];   // swizzled (copied as-is)
  __shared__ unsigned short t_lds[ROWS][128];   // swizzled
  const int tid = threadIdx.x;
  const int rbase = blockIdx.x * ROWS;

  {
    // ---- stage X tile: x_ws is already tile-swizzled -> linear 16B copies
    const bf16x8* xsrc = (const bf16x8*)(x_ws + (size_t)rbase * 256);
    bf16x8* xdst = (bf16x8*)&x_lds[0][0];
#pragma unroll
    for (int i = 0; i < 4; i++)
      xdst[tid + i * 512] = xsrc[tid + i * 512];

    // ---- tri + LN: 8 threads/row; thread j owns chunks {j, j+8} ----
    const int r = tid >> 3, j = tid & 7;
    const int row = rbase + r;
    const int k12 = row % 12;
    const unsigned short* ar = a_ws + (size_t)row * 128;
    const float* bs = bsum + k12 * 128;
    float tv[16];
    float s1 = 0.f, s2 = 0.f;
#pragma unroll
    for (int i = 0; i < 2; i++) {
      const int e = (j + 8 * i) * 8;
      const ushort4 a0 = *(const ushort4*)(ar + e);
      const ushort4 a1 = *(const ushort4*)(ar + e + 4);
      const float4 b0 = *(const float4*)(bs + e);
      const float4 b1 = *(const float4*)(bs + e + 4);
      const float t0 = bf2f(a0.x) * b0.x, t1 = bf2f(a0.y) * b0.y;
      const float t2 = bf2f(a0.z) * b0.z, t3 = bf2f(a0.w) * b0.w;
      const float t4 = bf2f(a1.x) * b1.x, t5 = bf2f(a1.y) * b1.y;
      const float t6 = bf2f(a1.z) * b1.z, t7 = bf2f(a1.w) * b1.w;
      tv[8*i+0] = t0; tv[8*i+1] = t1; tv[8*i+2] = t2; tv[8*i+3] = t3;
      tv[8*i+4] = t4; tv[8*i+5] = t5; tv[8*i+6] = t6; tv[8*i+7] = t7;
      s1 += t0 + t1 + t2 + t3 + t4 + t5 + t6 + t7;
      s2 += t0*t0 + t1*t1 + t2*t2 + t3*t3 + t4*t4 + t5*t5 + t6*t6 + t7*t7;
    }
    s1 += __shfl_xor(s1, 1); s1 += __shfl_xor(s1, 2); s1 += __shfl_xor(s1, 4);
    s2 += __shfl_xor(s2, 1); s2 += __shfl_xor(s2, 2); s2 += __shfl_xor(s2, 4);
    const float mu = s1 * (1.f / 128.f);
    const float rstd = rsqrtf(s2 * (1.f / 128.f) - mu * mu + 1e-5f);
    const int jp = j ^ (r & 7);
#pragma unroll
    for (int i = 0; i < 2; i++) {
      const int e = (j + 8 * i) * 8;
      const float4 g0 = *(const float4*)(ln_g + e);
      const float4 g1 = *(const float4*)(ln_g + e + 4);
      const float4 c0 = *(const float4*)(ln_b + e);
      const float4 c1 = *(const float4*)(ln_b + e + 4);
      bf16x8 h;
      h[0] = (short)f2bf((tv[8*i+0] - mu) * rstd * g0.x + c0.x);
      h[1] = (short)f2bf((tv[8*i+1] - mu) * rstd * g0.y + c0.y);
      h[2] = (short)f2bf((tv[8*i+2] - mu) * rstd * g0.z + c0.z);
      h[3] = (short)f2bf((tv[8*i+3] - mu) * rstd * g0.w + c0.w);
      h[4] = (short)f2bf((tv[8*i+4] - mu) * rstd * g1.x + c1.x);
      h[5] = (short)f2bf((tv[8*i+5] - mu) * rstd * g1.y + c1.y);
      h[6] = (short)f2bf((tv[8*i+6] - mu) * rstd * g1.z + c1.z);
      h[7] = (short)f2bf((tv[8*i+7] - mu) * rstd * g1.w + c1.w);
      *(bf16x8*)&t_lds[r][(jp + 8 * i) * 8] = h;
    }
  }
  __syncthreads();

  const int wv = tid >> 6, lane = tid & 63;
  const int m = lane & 15, q = lane >> 4;

  f32x4 ag[4][2], al[4][2];
#pragma unroll
  for (int a = 0; a < 4; a++)
#pragma unroll
    for (int b = 0; b < 2; b++) { ag[a][b] = (f32x4){0.f,0.f,0.f,0.f}; al[a][b] = (f32x4){0.f,0.f,0.f,0.f}; }

  // gate GEMM: X[64,256] @ Wgo^T (32 out-chans per wave), A from LDS
#pragma unroll
  for (int kb = 0; kb < 8; kb++) {
    bf16x8 A[4], B[2];
#pragma unroll
    for (int mt = 0; mt < 4; mt++)
      A[mt] = *(const bf16x8*)&x_lds[mt * 16 + m][((kb * 4 + q) ^ (m & 7)) << 3];
#pragma unroll
    for (int nt = 0; nt < 2; nt++)
      B[nt] = *(const bf16x8*)(wgo + ((((wv * 8 + kb) * 2 + nt) * 64 + lane) << 3));
#pragma unroll
    for (int nt = 0; nt < 2; nt++)
#pragma unroll
      for (int mt = 0; mt < 4; mt++)
        ag[mt][nt] = __builtin_amdgcn_mfma_f32_16x16x32_bf16(A[mt], B[nt], ag[mt][nt], 0, 0, 0);
  }
  // lin GEMM: T[64,128] @ Wlo^T, A from LDS
#pragma unroll
  for (int kb = 0; kb < 4; kb++) {
    bf16x8 A[4], B[2];
#pragma unroll
    for (int mt = 0; mt < 4; mt++)
      A[mt] = *(const bf16x8*)&t_lds[mt * 16 + m][((kb * 4 + q) ^ (m & 7)) << 3];
#pragma unroll
    for (int nt = 0; nt < 2; nt++)
      B[nt] = *(const bf16x8*)(wlo + ((((wv * 4 + kb) * 2 + nt) * 64 + lane) << 3));
#pragma unroll
    for (int nt = 0; nt < 2; nt++)
#pragma unroll
      for (int mt = 0; mt < 4; mt++)
        al[mt][nt] = __builtin_amdgcn_mfma_f32_16x16x32_bf16(A[mt], B[nt], al[mt][nt], 0, 0, 0);
  }

  // ---- epilogue ----
#pragma unroll
  for (int nt = 0; nt < 2; nt++) {
    const int n = wv * 32 + nt * 16 + m;
    const float bgo = b_go[n], blo = b_lo[n];
#pragma unroll
    for (int mt = 0; mt < 4; mt++) {
#pragma unroll
      for (int rg = 0; rg < 4; rg++) {
        const int row = rbase + mt * 16 + q * 4 + rg;
        const float gv = ag[mt][nt][rg] + bgo;
        const float lv = al[mt][nt][rg] + blo;
        out[(size_t)row * 256 + n] = lv / (1.f + __expf(-gv));
      }
    }
  }
}

// ---------------------------------------------------------------------------
extern "C" void kernel_launch(void* const* d_in, const int* in_sizes, int n_in,
                              void* d_out, int out_size, void* d_ws, size_t ws_size,
                              hipStream_t stream) {
  (void)in_sizes; (void)n_in; (void)out_size; (void)ws_size;
  const float* values  = (const float*)d_in[0];
  const float* ln_in_g = (const float*)d_in[1];
  const float* ln_in_b = (const float*)d_in[2];
  const float* W_ga = (const float*)d_in[3];
  const float* b_ga = (const float*)d_in[4];
  const float* W_la = (const float*)d_in[5];
  const float* b_la = (const float*)d_in[6];
  const float* W_gb = (const float*)d_in[7];
  const float* b_gb = (const float*)d_in[8];
  const float* W_lb = (const float*)d_in[9];
  const float* b_lb = (const float*)d_in[10];
  const float* ln_o_g = (const float*)d_in[11];
  const float* ln_o_b = (const float*)d_in[12];
  const float* W_go = (const float*)d_in[13];
  const float* b_go = (const float*)d_in[14];
  const float* W_lo = (const float*)d_in[15];
  const float* b_lo = (const float*)d_in[16];
  // d_in[17] = indices: unused by the reference.

  // workspace layout (184,981,504 bytes, all offsets 256B-aligned) — unchanged
  char* ws = (char*)d_ws;
  unsigned short* x_ws  = (unsigned short*)(ws + 0);          // 240000*256*2
  unsigned short* a_ws  = (unsigned short*)(ws + 122880000);  // 240000*128*2
  unsigned short* wcat  = (unsigned short*)(ws + 184320000);  // 512*256*2
  unsigned short* wgo16 = (unsigned short*)(ws + 184582144);  // 256*256*2
  unsigned short* wlo16 = (unsigned short*)(ws + 184713216);  // 256*128*2
  float*          bsum  = (float*)        (ws + 184778752);   // 12*128*4
  float*          bpart = (float*)        (ws + 184784896);   // 32*1536*4

  hipLaunchKernelGGL(prep_kernel, dim3(896), dim3(256), 0, stream,
                     W_ga, W_la, W_gb, W_lb, W_go, W_lo, wcat, wgo16, wlo16,
                     bsum, bpart);
  hipLaunchKernelGGL(k1_kernel, dim3(NBLK), dim3(512), 0, stream,
                     values, ln_in_g, ln_in_b, b_ga, b_la, b_gb, b_lb,
                     wcat, x_ws, a_ws, bpart);
  hipLaunchKernelGGL(reduce_kernel, dim3(6), dim3(256), 0, stream,
                     bpart, bsum);
  hipLaunchKernelGGL(k2_kernel, dim3(NBLK), dim3(512), 0, stream,
                     x_ws, a_ws, bsum, ln_o_g, ln_o_b, wgo16, wlo16, b_go, b_lo,
                     (float*)d_out);
}